// Round 1
// baseline (346.373 us; speedup 1.0000x reference)
//
#include <hip/hip_runtime.h>

typedef unsigned short u16;
typedef __attribute__((ext_vector_type(8))) u16 u16x8;
typedef __attribute__((ext_vector_type(8))) __bf16 bf16x8;
typedef __attribute__((ext_vector_type(4))) float f32x4;

// d_out layout (floats): coefs | alpha | new_state | new_buf
#define ALPHA_OFF   3932160
#define NST_OFF     3936256
#define NBUF_OFF    6033408

__device__ __forceinline__ u16 f2bf(float f) {
  unsigned u = __builtin_bit_cast(unsigned, f);
  u += 0x7fffu + ((u >> 16) & 1u);
  return (u16)(u >> 16);
}
__device__ __forceinline__ float fsig(float x) { return 1.f / (1.f + __expf(-x)); }
__device__ __forceinline__ float ftanh(float x) {
  x = fminf(15.f, fmaxf(-15.f, x));
  float e = __expf(2.f * x);
  return (e - 1.f) / (e + 1.f);
}
__device__ __forceinline__ f32x4 mfma16(u16x8 a, u16x8 b, f32x4 c) {
  return __builtin_amdgcn_mfma_f32_16x16x32_bf16(
      __builtin_bit_cast(bf16x8, a), __builtin_bit_cast(bf16x8, b), c, 0, 0, 0);
}

// ---------------- K0: GRU weights -> bf16, transposed to [N=768][K=256] ----
__global__ __launch_bounds__(256) void wprep_kernel(
    const float* __restrict__ k0, const float* __restrict__ rk0,
    const float* __restrict__ k1, const float* __restrict__ rk1,
    u16* __restrict__ kT) {
  __shared__ u16 tl[64][65];
  int nb = blockIdx.x, kb = blockIdx.y, m = blockIdx.z;
  const float* src = (m == 0) ? k0 : (m == 1) ? rk0 : (m == 2) ? k1 : rk1;
  u16* dst = kT + (size_t)m * 768 * 256;
  int tid = threadIdx.x;
  int c = tid & 63, r4 = tid >> 6;
  for (int rr = 0; rr < 64; rr += 4) {
    int k = kb * 64 + rr + r4, n = nb * 64 + c;
    tl[rr + r4][c] = f2bf(src[(size_t)k * 768 + n]);   // coalesced along n
  }
  __syncthreads();
  for (int rr = 0; rr < 64; rr += 4) {
    int n = nb * 64 + rr + r4, k = kb * 64 + c;
    dst[(size_t)n * 256 + k] = tl[c][rr + r4];         // coalesced along k
  }
}

// ---------------- K1: x_in = relu(grouped(emb,w_in)); bf16 copies ----------
__global__ __launch_bounds__(256) void prep_kernel(
    const float* __restrict__ emb, const float* __restrict__ dec,
    const float* __restrict__ w_in,
    float* __restrict__ x_f32, u16* __restrict__ x_q,
    u16* __restrict__ h0q, u16* __restrict__ h1q) {
  __shared__ float wl[8192];       // w_in [g][i][o]
  __shared__ float el[16][256];
  int tid = threadIdx.x, rowBase = blockIdx.x * 16;
  for (int i = tid; i < 8192; i += 256) wl[i] = w_in[i];
  for (int i = tid; i < 4096; i += 256)
    el[i >> 8][i & 255] = emb[(size_t)(rowBase + (i >> 8)) * 256 + (i & 255)];
  __syncthreads();
  int g = tid >> 5, o = tid & 31;
  for (int r = 0; r < 16; ++r) {
    float acc = 0.f;
#pragma unroll
    for (int i = 0; i < 32; ++i) acc += el[r][g * 32 + i] * wl[g * 1024 + i * 32 + o];
    acc = fmaxf(acc, 0.f);
    size_t p = (size_t)(rowBase + r) * 256 + tid;
    x_f32[p] = acc;
    x_q[p] = f2bf(acc);
  }
  for (int i = tid; i < 8192; i += 256) {
    int r = i >> 9, c = i & 511;
    float v = dec[(size_t)(rowBase + r) * 512 + c];
    if (c < 256) h0q[(size_t)(rowBase + r) * 256 + c] = f2bf(v);
    else         h1q[(size_t)(rowBase + r) * 256 + (c - 256)] = f2bf(v);
  }
}

// ---------------- K2/K3: fused GRU layer (MFMA bf16) -----------------------
// WG: 32 rows x 64 gate-cols. acc_z = x@k_z + h@rk_z (folded), acc_r likewise,
// xh and hh kept separate for cand = tanh(xh + r*hh).
template <int LAYER>
__global__ __launch_bounds__(256) void gru_kernel(
    const u16* __restrict__ xq, const u16* __restrict__ hq,
    const float* __restrict__ dec,
    const u16* __restrict__ kT, const u16* __restrict__ rkT,
    const float* __restrict__ bias,
    float* __restrict__ nst,            // d_out + NST_OFF  [4096][512]
    u16* __restrict__ outq,             // layer0 only
    const float* __restrict__ x_f32,    // layer1 only
    float* __restrict__ c_f32) {        // layer1 only
  __shared__ u16 lsA[2][32][40];        // [x|h] rows, 80B stride (16B aligned)
  __shared__ u16 lsB[2][192][40];       // [k|rk] cols: 64 z + 64 r + 64 h
  int tid = threadIdx.x;
  int wave = tid >> 6, lane = tid & 63;
  int m0 = lane & 15, quad = lane >> 4;
  int rowBase = blockIdx.x * 32;
  int jz = blockIdx.y * 64;
  int cw = wave * 16;
  f32x4 az0 = {0.f, 0.f, 0.f, 0.f}, az1 = az0, ar0 = az0, ar1 = az0;
  f32x4 axh0 = az0, axh1 = az0, ahh0 = az0, ahh1 = az0;

  for (int kk = 0; kk < 8; ++kk) {
    int k0 = kk * 32;
    __syncthreads();
#pragma unroll
    for (int it = 0; it < 7; ++it) {            // 7*256 = 1792 16B chunks
      int idx = tid + it * 256;
      const u16* src;
      u16* dst;
      if (idx < 256) {                          // A: 2 mats * 32 rows * 4
        int mat = idx >> 7, r = (idx >> 2) & 31, c4 = idx & 3;
        src = (mat ? hq : xq) + (size_t)(rowBase + r) * 256 + k0 + c4 * 8;
        dst = &lsA[mat][r][c4 * 8];
      } else {                                  // B: 2 mats * 192 rows * 4
        int j = idx - 256;
        int mat = (j >= 768);
        int jm = mat ? j - 768 : j;
        int rB = jm >> 2, c4 = jm & 3;
        int n = (rB >> 6) * 256 + jz + (rB & 63);
        src = (mat ? rkT : kT) + (size_t)n * 256 + k0 + c4 * 8;
        dst = &lsB[mat][rB][c4 * 8];
      }
      *(uint4*)dst = *(const uint4*)src;
    }
    __syncthreads();
    u16x8 ax0v = *(const u16x8*)&lsA[0][m0][quad * 8];
    u16x8 ax1v = *(const u16x8*)&lsA[0][16 + m0][quad * 8];
    u16x8 ah0v = *(const u16x8*)&lsA[1][m0][quad * 8];
    u16x8 ah1v = *(const u16x8*)&lsA[1][16 + m0][quad * 8];
    u16x8 bkz = *(const u16x8*)&lsB[0][cw + m0][quad * 8];
    u16x8 bkr = *(const u16x8*)&lsB[0][64 + cw + m0][quad * 8];
    u16x8 bkh = *(const u16x8*)&lsB[0][128 + cw + m0][quad * 8];
    u16x8 brz = *(const u16x8*)&lsB[1][cw + m0][quad * 8];
    u16x8 brr = *(const u16x8*)&lsB[1][64 + cw + m0][quad * 8];
    u16x8 brh = *(const u16x8*)&lsB[1][128 + cw + m0][quad * 8];
    az0 = mfma16(ax0v, bkz, az0);  az0 = mfma16(ah0v, brz, az0);
    az1 = mfma16(ax1v, bkz, az1);  az1 = mfma16(ah1v, brz, az1);
    ar0 = mfma16(ax0v, bkr, ar0);  ar0 = mfma16(ah0v, brr, ar0);
    ar1 = mfma16(ax1v, bkr, ar1);  ar1 = mfma16(ah1v, brr, ar1);
    axh0 = mfma16(ax0v, bkh, axh0); axh1 = mfma16(ax1v, bkh, axh1);
    ahh0 = mfma16(ah0v, brh, ahh0); ahh1 = mfma16(ah1v, brh, ahh1);
  }

  int col = jz + cw + m0;
  float bz = bias[col] + bias[768 + col];
  float br = bias[256 + col] + bias[1024 + col];
  float bxh = bias[512 + col];
  float bhh = bias[1280 + col];
  const int hoff = LAYER ? 256 : 0;
#pragma unroll
  for (int t = 0; t < 2; ++t) {
    f32x4 vz = t ? az1 : az0, vr = t ? ar1 : ar0;
    f32x4 vxh = t ? axh1 : axh0, vhh = t ? ahh1 : ahh0;
#pragma unroll
    for (int i = 0; i < 4; ++i) {
      int row = rowBase + t * 16 + quad * 4 + i;   // C/D: col=lane&15, row=quad*4+reg
      float h = dec[(size_t)row * 512 + hoff + col];
      float z = fsig(vz[i] + bz);
      float r = fsig(vr[i] + br);
      float cand = ftanh(vxh[i] + bxh + r * (vhh[i] + bhh));
      float o = z * h + (1.f - z) * cand;
      nst[(size_t)row * 512 + hoff + col] = o;
      if (LAYER == 0) {
        outq[(size_t)row * 256 + col] = f2bf(o);
      } else {
        float c = o + x_f32[(size_t)row * 256 + col];
        c_f32[(size_t)row * 256 + col] = c;
      }
    }
  }
}

// ---------------- K4: tanh(grouped(c,w_out)) -> flat temp in coefs region --
__global__ __launch_bounds__(256) void wout_kernel(
    const float* __restrict__ c_f32, const float* __restrict__ w_out,
    float* __restrict__ outc) {
  __shared__ float cs[16][256];
  int tid = threadIdx.x, rowBase = blockIdx.x * 16;
  for (int i = tid; i < 4096; i += 256)
    cs[i >> 8][i & 255] = c_f32[(size_t)(rowBase + (i >> 8)) * 256 + (i & 255)];
  __syncthreads();
  for (int flat = tid; flat < 960; flat += 256) {
    int g = flat / 120, og = flat % 120;
    float acc[16];
#pragma unroll
    for (int r = 0; r < 16; ++r) acc[r] = 0.f;
    for (int i = 0; i < 32; ++i) {
      float w = w_out[(size_t)g * 3840 + i * 120 + og];
#pragma unroll
      for (int r = 0; r < 16; ++r) acc[r] += cs[r][g * 32 + i] * w;
    }
#pragma unroll
    for (int r = 0; r < 16; ++r)
      outc[(size_t)(rowBase + r) * 960 + flat] = ftanh(acc[r]);
  }
}

// ---------------- K5: conv+pw+BN+relu + combine + alpha + new_buf ----------
__global__ __launch_bounds__(256) void head_kernel(
    const float* __restrict__ convp, const float* __restrict__ c0,
    const float* __restrict__ c_f32,
    const float* __restrict__ conv_w, const float* __restrict__ pw_w,
    const float* __restrict__ bng, const float* __restrict__ bnb,
    const float* __restrict__ bnm, const float* __restrict__ bnv,
    const float* __restrict__ fca_w, const float* __restrict__ fca_b,
    float* __restrict__ outp) {
  __shared__ float xs[5 * 96 * 16];
  __shared__ float cs[256];
  __shared__ float ybuf[96][10];
  __shared__ float cw[400];
  __shared__ float pw[100];
  __shared__ float bscale[10], bshift[10];
  __shared__ float fca[256];
  __shared__ float ared[4];
  int tid = threadIdx.x, lane = tid & 63, wave = tid >> 6;
  for (int i = tid; i < 400; i += 256) cw[i] = conv_w[i];
  if (tid < 100) pw[tid] = pw_w[tid];
  if (tid < 10) {
    float s = bng[tid] * rsqrtf(bnv[tid] + 1e-3f);
    bscale[tid] = s;
    bshift[tid] = bnb[tid] - bnm[tid] * s;
  }
  fca[tid] = fca_w[tid];
  float4* nb4 = (float4*)(outp + NBUF_OFF);
  const float4* cp4 = (const float4*)convp;
  const float4* c04 = (const float4*)c0;

  for (int rr = 0; rr < 2; ++rr) {
    int b = blockIdx.x * 2 + rr;
    __syncthreads();
    // stage x = [convp | c0] once; new_buf write shares the same read
    for (int i = tid; i < 1920; i += 256) {
      int t = i / 384, p = i % 384;
      float4 v = (t < 4) ? cp4[(size_t)b * 1536 + i] : c04[(size_t)b * 384 + p];
      ((float4*)xs)[i] = v;
      if (t >= 1) nb4[(size_t)b * 1536 + (size_t)(t - 1) * 384 + p] = v;
    }
    if (tid < 64) ((float4*)cs)[tid] = ((const float4*)c_f32)[(size_t)b * 64 + tid];
    __syncthreads();
    // grouped depth conv -> ybuf
    for (int u = tid; u < 960; u += 256) {
      int f = u / 10, oc = u % 10;
      int xo = (oc >= 5) ? 8 : 0;
      float acc = 0.f;
#pragma unroll
      for (int t = 0; t < 5; ++t)
#pragma unroll
        for (int i = 0; i < 8; ++i)
          acc += xs[t * 1536 + f * 16 + xo + i] * cw[t * 80 + i * 10 + oc];
      ybuf[f][oc] = acc;
    }
    // alpha = sigmoid(c . fc_a_w + b)
    float ap = cs[tid] * fca[tid];
#pragma unroll
    for (int off = 32; off > 0; off >>= 1) ap += __shfl_down(ap, off, 64);
    if (lane == 0) ared[wave] = ap;
    __syncthreads();
    if (tid == 0)
      outp[ALPHA_OFF + b] = fsig(ared[0] + ared[1] + ared[2] + ared[3] + fca_b[0]);
    // pw + BN + relu + add tanh-term (read flat temp), then rewrite in coefs order
    float vals[4];
    int nv = 0;
    for (int u2 = tid; u2 < 480; u2 += 256) {
      int o = u2 / 96, f = u2 % 96;
#pragma unroll
      for (int q = 0; q < 2; ++q) {
        int p = o * 2 + q;
        float y2 = 0.f;
#pragma unroll
        for (int j = 0; j < 10; ++j) y2 += ybuf[f][j] * pw[j * 10 + p];
        float bnr = fmaxf(y2 * bscale[p] + bshift[p], 0.f);
        float wt = outp[(size_t)b * 960 + f * 10 + p];   // flat temp from wout_kernel
        vals[nv++] = bnr + wt;
      }
    }
    __syncthreads();   // all flat-temp reads done before overwrite
    nv = 0;
    for (int u2 = tid; u2 < 480; u2 += 256) {
      int o = u2 / 96, f = u2 % 96;
      outp[(size_t)b * 960 + o * 192 + f * 2 + 0] = vals[nv++];
      outp[(size_t)b * 960 + o * 192 + f * 2 + 1] = vals[nv++];
    }
  }
}

// ---------------------------------------------------------------------------
extern "C" void kernel_launch(void* const* d_in, const int* in_sizes, int n_in,
                              void* d_out, int out_size, void* d_ws, size_t ws_size,
                              hipStream_t stream) {
  const float* emb    = (const float*)d_in[0];
  const float* c0     = (const float*)d_in[1];
  const float* dec    = (const float*)d_in[2];
  const float* convp  = (const float*)d_in[3];
  const float* w_in   = (const float*)d_in[4];
  const float* gk0    = (const float*)d_in[5];
  const float* grk0   = (const float*)d_in[6];
  const float* gb0    = (const float*)d_in[7];
  const float* gk1    = (const float*)d_in[8];
  const float* grk1   = (const float*)d_in[9];
  const float* gb1    = (const float*)d_in[10];
  const float* w_out  = (const float*)d_in[11];
  const float* fca_w  = (const float*)d_in[12];
  const float* fca_b  = (const float*)d_in[13];
  const float* conv_w = (const float*)d_in[14];
  const float* pw_w   = (const float*)d_in[15];
  const float* bng    = (const float*)d_in[16];
  const float* bnb    = (const float*)d_in[17];
  const float* bnm    = (const float*)d_in[18];
  const float* bnv    = (const float*)d_in[19];
  float* out = (float*)d_out;
  char* ws = (char*)d_ws;
  // workspace layout (bytes)
  float* x_f32 = (float*)(ws + 0);           // 4 MB
  float* c_f32 = (float*)(ws + 4194304);     // 4 MB
  u16*   x_q   = (u16*)(ws + 8388608);       // 2 MB
  u16*   h0q   = (u16*)(ws + 10485760);      // 2 MB
  u16*   h1q   = (u16*)(ws + 12582912);      // 2 MB
  u16*   o0q   = (u16*)(ws + 14680064);      // 2 MB
  u16*   kT    = (u16*)(ws + 16777216);      // 4 * 768*256 u16 = 1.5 MB

  wprep_kernel<<<dim3(12, 4, 4), 256, 0, stream>>>(gk0, grk0, gk1, grk1, kT);
  prep_kernel<<<dim3(256), 256, 0, stream>>>(emb, dec, w_in, x_f32, x_q, h0q, h1q);
  gru_kernel<0><<<dim3(128, 4), 256, 0, stream>>>(x_q, h0q, dec, kT, kT + 196608,
                                                  gb0, out + NST_OFF, o0q, nullptr, nullptr);
  gru_kernel<1><<<dim3(128, 4), 256, 0, stream>>>(o0q, h1q, dec, kT + 2 * 196608, kT + 3 * 196608,
                                                  gb1, out + NST_OFF, nullptr, x_f32, c_f32);
  wout_kernel<<<dim3(256), 256, 0, stream>>>(c_f32, w_out, out);
  head_kernel<<<dim3(2048), 256, 0, stream>>>(convp, c0, c_f32, conv_w, pw_w,
                                              bng, bnb, bnm, bnv, fca_w, fca_b, out);
}